// Round 1
// baseline (233.352 us; speedup 1.0000x reference)
//
#include <hip/hip_runtime.h>

// Sepconv: out[b,c,y,x] = sum_{i,j} In[b,c,y*F+i,x*F+j] * V[b,i,y,x] * H[b,j,y,x]
// B=8, C=3, F=5, HO=WO=256. All fp32. Memory-bound (~174 MB traffic, ~28 us floor).
//
// v2: LDS-staged. One block = one (b,c,y) row. The 5 input rows a block needs
// are one contiguous 25.6 KB span -> stage with coalesced float4 loads
// (7 vector loads/thread) instead of 25 strided scalar loads/thread.
// LDS compute reads at float-stride 5: gcd(5,32)=1 -> conflict-free per
// 32-lane group (2-way wave64 aliasing is free).

#define Bsz 8
#define Csz 3
#define Fsz 5
#define HOsz 256
#define WOsz 256

__global__ __launch_bounds__(256) void sepconv_kernel(
    const float* __restrict__ in,   // [B,C,HO*F,WO*F]
    const float* __restrict__ V,    // [B,F,HO,WO]
    const float* __restrict__ Hh,   // [B,F,HO,WO]
    float* __restrict__ out)        // [B,C,HO,WO]
{
    constexpr int W = WOsz * Fsz;          // 1280 (input row width, floats)
    constexpr int PLANE = HOsz * WOsz;     // 65536
    constexpr int ROW_FLOATS = Fsz * W;    // 6400 floats = 25.6 KB
    constexpr int NV4 = ROW_FLOATS / 4;    // 1600 float4
    __shared__ float tile[ROW_FLOATS];

    const int tid = threadIdx.x;           // 256 threads = 256 x positions
    const int y   = blockIdx.x & (HOsz - 1);
    const int bc  = blockIdx.x >> 8;       // b*C + c, 0..23
    const int c   = bc % Csz;
    const int b   = bc / Csz;
    const int x   = tid;

    // ---- Stage 5 input rows (one contiguous 25.6 KB block) into LDS ----
    // Row base offset is a multiple of 1280 floats -> 16B aligned, float4 ok.
    const float4* src = reinterpret_cast<const float4*>(
        in + ((size_t)(b * Csz + c) * (HOsz * Fsz) + (size_t)y * Fsz) * W);
    float4* dst = reinterpret_cast<float4*>(tile);
#pragma unroll
    for (int k = 0; k < 6; ++k)            // 6*256 = 1536 float4
        dst[tid + k * 256] = src[tid + k * 256];
    if (tid < NV4 - 6 * 256)               // tail: 64 float4
        dst[tid + 6 * 256] = src[tid + 6 * 256];

    // ---- Weights (coalesced, independent of the staging -> overlaps) ----
    const float* vp = V  + (size_t)b * Fsz * PLANE + y * WOsz + x;
    const float* hp = Hh + (size_t)b * Fsz * PLANE + y * WOsz + x;
    float v[Fsz], h[Fsz];
#pragma unroll
    for (int i = 0; i < Fsz; ++i) {
        v[i] = vp[i * PLANE];
        h[i] = hp[i * PLANE];
    }

    __syncthreads();

    // ---- Compute from LDS ----
    float acc = 0.f;
#pragma unroll
    for (int i = 0; i < Fsz; ++i) {
        const float* r = tile + i * W + x * Fsz;
        float rs = r[0] * h[0];
        rs = fmaf(r[1], h[1], rs);
        rs = fmaf(r[2], h[2], rs);
        rs = fmaf(r[3], h[3], rs);
        rs = fmaf(r[4], h[4], rs);
        acc = fmaf(rs, v[i], acc);
    }

    out[((size_t)bc * HOsz + y) * WOsz + x] = acc;
}

extern "C" void kernel_launch(void* const* d_in, const int* in_sizes, int n_in,
                              void* d_out, int out_size, void* d_ws, size_t ws_size,
                              hipStream_t stream) {
    const float* in = (const float*)d_in[0];
    const float* V  = (const float*)d_in[1];
    const float* Hh = (const float*)d_in[2];
    float* out = (float*)d_out;

    const int grid = Bsz * Csz * HOsz;     // 6144 blocks, one per (b,c,y)
    sepconv_kernel<<<grid, 256, 0, stream>>>(in, V, Hh, out);
}